// Round 7
// baseline (399.256 us; speedup 1.0000x reference)
//
#include <hip/hip_runtime.h>

// ---------------- constants ----------------
#define BTOT   4096
#define DATA   16
#define HID    64
#define VFW    128
#define LAB    10
#define TPTS   201
#define NSEG   200
#define NSTEPS 100
#define MT     16            // batch rows per block
#define NBLK   (BTOT / MT)   // 256
#define YS     68            // padded fp32 stride for y32 (logits staging only)

typedef __attribute__((ext_vector_type(8))) short short8;   // 8 bf16
typedef __attribute__((ext_vector_type(4))) float f32x4;
typedef __attribute__((ext_vector_type(2))) unsigned uint2v;

#define LOG2E  1.4426950408889634f
#define K2L    (2.0f * LOG2E)

__device__ __forceinline__ short f2bf(float f) {
    unsigned u = __builtin_bit_cast(unsigned, f);
    u = (u + 0x7FFFu + ((u >> 16) & 1u)) >> 16;   // RNE
    return (short)u;
}

// pack two f32 -> two bf16 (RNE) in one VALU op
__device__ __forceinline__ unsigned cvt_pk_bf16(float lo, float hi) {
    unsigned r;
    asm("v_cvt_pk_bf16_f32 %0, %1, %2" : "=v"(r) : "v"(lo), "v"(hi));
    return r;
}

__device__ __forceinline__ float exp2_raw(float x) {
#if __has_builtin(__builtin_amdgcn_exp2f)
    return __builtin_amdgcn_exp2f(x);
#else
    return exp2f(x);
#endif
}

// ---- LDS bank-conflict swizzles (32-short = 64B blocks, XOR'd by row) ----
// h-buffers: stride 136 shorts, 4 k-blocks; ybf: stride 72 shorts, 2 k-blocks.
// Same involution on write and read sides.
__device__ __forceinline__ int hidx(int row, int kb, int off) {
    return row * 136 + ((kb ^ (row & 3)) << 5) + off;
}
__device__ __forceinline__ int yidx(int row, int kb, int off) {
    return row * 72 + ((kb ^ (row & 1)) << 5) + off;
}

// ---------------- weight fragment packing ----------------
// slot index = (nt*KS + ks)*64 + lane ; each slot = 8 bf16 (16B)
// holding scale*W[16*nt + (lane&15)][32*ks + 8*(lane>>4) + j], j=0..7
// Serves as A-fragment (row=lane&15) and B-fragment (col=lane&15).
__global__ void pack_w(const float* __restrict__ W, short* __restrict__ outp,
                       int N, int K, float scale) {
    int tid = blockIdx.x * blockDim.x + threadIdx.x;
    int KS = K >> 5;
    int total = (N >> 4) * KS * 64;
    if (tid >= total) return;
    int ln = tid & 63;
    int fs = tid >> 6;
    int ks = fs % KS;
    int nt = fs / KS;
    int n  = nt * 16 + (ln & 15);
    int k0 = ks * 32 + (ln >> 4) * 8;
    const float* src = W + n * K + k0;
    short8 v;
#pragma unroll
    for (int j = 0; j < 8; ++j) v[j] = f2bf(scale * src[j]);
    *(((short8*)outp) + tid) = v;
}

// ---------------- persistent CDE kernel ----------------
__global__ __launch_bounds__(1024, 4) void cde_main(
    const float* __restrict__ ts_g,  const float* __restrict__ coeffs,
    const float* __restrict__ x0,    const float* __restrict__ lin1_w,
    const float* __restrict__ lin1_b,
    const float* __restrict__ b0g,   const float* __restrict__ b1g,
    const float* __restrict__ b2g,   const float* __restrict__ l2w,
    const float* __restrict__ l2b,
    const short8* __restrict__ w0p,  const short8* __restrict__ w1p,
    const short8* __restrict__ w2p,  float* __restrict__ out)
{
    __shared__ float ts_sh[TPTS];
    __shared__ float ttab[NSTEPS + 1];
    __shared__ float cdtab[(NSTEPS + 1) * DATA];
    __shared__ float cdqtab[(NSTEPS + 1) * 4];       // per-quad sums of cd
    __shared__ float y32[MT * YS];                   // logits staging only
    __shared__ __align__(16) short ybf[MT * 72];     // 16x64 bf16, swizzled blocks
    __shared__ __align__(16) short h1bf[MT * 136];   // 16x128 bf16, swizzled blocks
    __shared__ __align__(16) short h2bf[MT * 136];
    __shared__ float b2s[HID * DATA];                // 2*log2e*b2 (MFMA C-init)
    __shared__ __align__(16) short w0f[1024 * 8];    // w0 frags (16KB)
    __shared__ __align__(16) short w1f[2048 * 8];    // w1 frags (32KB)
    __shared__ float lgts[MT * 12];

    const int tid  = threadIdx.x;
    const int lane = tid & 63;
    const int wave = tid >> 6;       // 0..15
    const int lm   = lane & 15;
    const int lg   = lane >> 4;      // 0..3
    const int row0 = blockIdx.x * MT;

    // ---- phase 0: ts ----
    for (int i = tid; i < TPTS; i += 1024) ts_sh[i] = ts_g[i];
    __syncthreads();

    const float dtv = (ts_sh[TPTS - 1] - ts_sh[0]) / 100.0f;
    const float half_dt = 0.5f * dtv;

    // ---- phase 1: ttab (exact serial t chain) + misc init ----
    if (tid == 0) {
        float tv = ts_sh[0];
        ttab[0] = tv;
        for (int s = 0; s < NSTEPS; ++s) { tv = tv + dtv; ttab[s + 1] = tv; }
    }
    for (int i = tid; i < HID * DATA; i += 1024) b2s[i] = K2L * b2g[i];
    for (int i = tid; i < 1024; i += 1024) ((short8*)w0f)[i] = w0p[i];
    for (int i = tid; i < 2048; i += 1024) ((short8*)w1f)[i] = w1p[i];

    // ---- per-lane y-state: lane (lm,lg) of wave owns y[m=lm][col=wave*4+lg] ----
    const int ycol = wave * 4 + lg;
    float yreg;
    {
        float s = lin1_b[ycol];
        const float* xr = x0 + (row0 + lm) * DATA;
        const float* wr = lin1_w + ycol * DATA;
#pragma unroll
        for (int k = 0; k < DATA; ++k) s += xr[k] * wr[k];
        yreg = s;
        ybf[yidx(lm, ycol >> 5, ycol & 31)] = f2bf(s);
    }
    __syncthreads();

    // ---- phase 2: cd table (exact reference formula, hoisted) ----
    for (int idx = tid; idx < (NSTEPS + 1) * DATA; idx += 1024) {
        float tv = ttab[idx >> 4];
        int d = idx & 15;
        int g  = (int)(tv * 200.0f);
        int i0 = g - 2; i0 = i0 < 0 ? 0 : (i0 > 196 ? 196 : i0);
        float v0 = ts_sh[i0 + 1], v1 = ts_sh[i0 + 2], v2 = ts_sh[i0 + 3], v3 = ts_sh[i0 + 4];
        int aidx = i0 + (v0 < tv) + (v1 < tv) + (v2 < tv) + (v3 < tv);
        aidx = aidx > (NSEG - 1) ? (NSEG - 1) : aidx;
        float dtl = tv - ts_sh[aidx];
        const f32x4 cc = *(const f32x4*)(coeffs + (aidx * DATA + d) * 4);
        cdtab[idx] = cc[0] + dtl * (cc[1] + dtl * (cc[2] + dtl * cc[3]));
    }
    __syncthreads();
    for (int idx = tid; idx < (NSTEPS + 1) * 4; idx += 1024) {
        const f32x4 c = *(const f32x4*)&cdtab[idx * 4];
        cdqtab[idx] = (c[0] + c[1]) + (c[2] + c[3]);
    }

    // ---- w2 -> registers (persistent, 64 VGPR/AGPR; pre-scaled by 2log2e) ----
    short8 w2r[4][4];
#pragma unroll
    for (int i = 0; i < 4; ++i)
#pragma unroll
        for (int ks = 0; ks < 4; ++ks)
            w2r[i][ks] = w2p[((wave * 4 + i) * 4 + ks) * 64 + lane];
    // bias as per-lane f32x4 (C-init for swapped G1/G2: rows n = base + 4lg + r)
    const f32x4 bias4 = (wave < 8)
        ? *(const f32x4*)&b0g[wave * 16 + 4 * lg]
        : *(const f32x4*)&b1g[(wave - 8) * 16 + 4 * lg];
    __syncthreads();

    // evalVF: K = k[m=lm][h=wave*4+lg] (lane-local result)
    auto evalVF = [&](int tidx) -> float {
        // ---- GEMM1 swapped (waves 0-7): D[n][m] = w0(16x64-tile) x y^T ----
        if (wave < 8) {
            short8 yb0 = *(const short8*)&ybf[yidx(lm, 0, lg * 8)];
            short8 yb1 = *(const short8*)&ybf[yidx(lm, 1, lg * 8)];
            short8 ws0 = ((const short8*)w0f)[(wave * 2 + 0) * 64 + lane];
            short8 ws1 = ((const short8*)w0f)[(wave * 2 + 1) * 64 + lane];
            f32x4 acc1 = bias4;
            acc1 = __builtin_amdgcn_mfma_f32_16x16x32_bf16(ws0, yb0, acc1, 0, 0, 0);
            acc1 = __builtin_amdgcn_mfma_f32_16x16x32_bf16(ws1, yb1, acc1, 0, 0, 0);
            // rows n = wave*16 + 4lg + r contiguous -> one b64 store (swizzled)
            int col = wave * 16 + 4 * lg;
            unsigned lo = cvt_pk_bf16(fmaxf(acc1[0], 0.f), fmaxf(acc1[1], 0.f));
            unsigned hi = cvt_pk_bf16(fmaxf(acc1[2], 0.f), fmaxf(acc1[3], 0.f));
            uint2v st; st[0] = lo; st[1] = hi;
            *(uint2v*)&h1bf[hidx(lm, col >> 5, col & 31)] = st;
        }
        __syncthreads();
        // all waves: control-deriv fragment + quad-sum (broadcast reads)
        const f32x4 cdr = *(const f32x4*)&cdtab[tidx * DATA + 4 * lg];
        const float sumcd = cdqtab[tidx * 4 + lg];
        // ---- GEMM2 swapped (waves 8-15): D[n][m] = w1(16x128-tile) x h1^T ----
        if (wave >= 8) {
            const int nt = wave - 8;
            f32x4 a = bias4;
            f32x4 b = {0.f, 0.f, 0.f, 0.f};
#pragma unroll
            for (int ks = 0; ks < 2; ++ks) {
                short8 h0 = *(const short8*)&h1bf[hidx(lm, 2 * ks + 0, lg * 8)];
                short8 h1 = *(const short8*)&h1bf[hidx(lm, 2 * ks + 1, lg * 8)];
                short8 ws0 = ((const short8*)w1f)[(nt * 4 + 2 * ks) * 64 + lane];
                short8 ws1 = ((const short8*)w1f)[(nt * 4 + 2 * ks + 1) * 64 + lane];
                a = __builtin_amdgcn_mfma_f32_16x16x32_bf16(ws0, h0, a, 0, 0, 0);
                b = __builtin_amdgcn_mfma_f32_16x16x32_bf16(ws1, h1, b, 0, 0, 0);
            }
            f32x4 acc2 = a + b;
            int col = nt * 16 + 4 * lg;
            unsigned lo = cvt_pk_bf16(fmaxf(acc2[0], 0.f), fmaxf(acc2[1], 0.f));
            unsigned hi = cvt_pk_bf16(fmaxf(acc2[2], 0.f), fmaxf(acc2[3], 0.f));
            uint2v st; st[0] = lo; st[1] = hi;
            *(uint2v*)&h2bf[hidx(lm, col >> 5, col & 31)] = st;
        }
        __syncthreads();
        // ---- GEMM3 (all 16 waves, 4 n-tiles each) + tanh + contraction ----
        // w2/b2 pre-scaled by 2log2e: acc IS the exp2 argument.
        short8 hb[4];
#pragma unroll
        for (int ks = 0; ks < 4; ++ks)
            hb[ks] = *(const short8*)&h2bf[hidx(lm, ks, lg * 8)];
        float p0, p1, p2, p3;
#pragma unroll
        for (int i = 0; i < 4; ++i) {
            int nb = (wave * 4 + i) * 16 + 4 * lg;        // n = h*16 + d, d = 4lg+r
            f32x4 acc = *(const f32x4*)&b2s[nb];          // scaled bias as C-init
#pragma unroll
            for (int ks = 0; ks < 4; ++ks)
                acc = __builtin_amdgcn_mfma_f32_16x16x32_bf16(w2r[i][ks], hb[ks], acc, 0, 0, 0);
            float csum = 0.f;
#pragma unroll
            for (int r = 0; r < 4; ++r) {
                // tanh(x) = 1 - 2/(e^{2x}+1);  e^{2x} = 2^acc (pre-scaled)
                float e  = exp2_raw(acc[r]);
                float rc = __builtin_amdgcn_rcpf(e + 1.0f);
                csum = __builtin_fmaf(cdr[r], rc, csum);
            }
            float sv = __builtin_fmaf(csum, -2.0f, sumcd); // p_i at (m=lm, d-quad=lg)
            if (i == 0) p0 = sv; else if (i == 1) p1 = sv;
            else if (i == 2) p2 = sv; else p3 = sv;
        }
        // ---- transpose-reduce over lg: K = sum_lg' p_{lg}(lg') lands at lane lg ----
        bool g1 = (lg & 1) != 0;
        float a4 = (lg & 2) ? p2 : p0;
        float b4 = (lg & 2) ? p3 : p1;
        float c4 = (lg & 2) ? p0 : p2;
        float d4 = (lg & 2) ? p1 : p3;
        float pg  = g1 ? b4 : a4;      // p[g]
        float pg1 = g1 ? a4 : b4;      // p[g^1]
        float pg2 = g1 ? d4 : c4;      // p[g^2]
        float pg3 = g1 ? c4 : d4;      // p[g^3]
        float s1  = pg  + __shfl_xor(pg1, 16);
        float s1b = pg2 + __shfl_xor(pg3, 16);
        return s1 + __shfl_xor(s1b, 32);
    };

    // ---- Heun time loop (y fully register-resident, lane-local) ----
    const int yboff = yidx(lm, ycol >> 5, ycol & 31);
    for (int s = 0; s < NSTEPS; ++s) {
        float K1 = evalVF(s);
        ybf[yboff] = (short)cvt_pk_bf16(__builtin_fmaf(dtv, K1, yreg), 0.f);
        yreg = __builtin_fmaf(half_dt, K1, yreg);             // y + dt/2*k1
        __syncthreads();
        float K2 = evalVF(s + 1);
        yreg = __builtin_fmaf(half_dt, K2, yreg);             // full Heun update
        ybf[yboff] = (short)cvt_pk_bf16(yreg, 0.f);
        __syncthreads();
    }

    // ---- logits + softmax (fp32 scalar) ----
    y32[lm * YS + ycol] = yreg;
    __syncthreads();
    if (tid < MT * LAB) {
        int m = tid / LAB, j = tid % LAB;
        float s = l2b[j];
        const float* wr = l2w + j * HID;
#pragma unroll
        for (int h = 0; h < HID; ++h) s += y32[m * YS + h] * wr[h];
        lgts[m * 12 + j] = s;
    }
    __syncthreads();
    if (tid < MT) {
        int m = tid;
        float mx = lgts[m * 12];
#pragma unroll
        for (int j = 1; j < LAB; ++j) mx = fmaxf(mx, lgts[m * 12 + j]);
        float e[LAB]; float sum = 0.f;
#pragma unroll
        for (int j = 0; j < LAB; ++j) { e[j] = __expf(lgts[m * 12 + j] - mx); sum += e[j]; }
#pragma unroll
        for (int j = 0; j < LAB; ++j) out[(row0 + m) * LAB + j] = e[j] / sum;
    }
}

extern "C" void kernel_launch(void* const* d_in, const int* in_sizes, int n_in,
                              void* d_out, int out_size, void* d_ws, size_t ws_size,
                              hipStream_t stream) {
    (void)in_sizes; (void)n_in; (void)out_size; (void)ws_size;
    const float* ts     = (const float*)d_in[0];
    const float* coeffs = (const float*)d_in[1];
    const float* x0     = (const float*)d_in[2];
    const float* lin1_w = (const float*)d_in[3];
    const float* lin1_b = (const float*)d_in[4];
    const float* w0     = (const float*)d_in[5];
    const float* b0     = (const float*)d_in[6];
    const float* w1     = (const float*)d_in[7];
    const float* b1     = (const float*)d_in[8];
    const float* w2     = (const float*)d_in[9];
    const float* b2     = (const float*)d_in[10];
    const float* l2w    = (const float*)d_in[11];
    const float* l2b    = (const float*)d_in[12];

    short* w0pack = (short*)d_ws;                           // 16 KB
    short* w1pack = (short*)((char*)d_ws + 16384);          // 32 KB
    short* w2pack = (short*)((char*)d_ws + 49152);          // 256 KB

    pack_w<<<dim3(4),  256, 0, stream>>>(w0, w0pack, 128, 64,  1.0f);
    pack_w<<<dim3(8),  256, 0, stream>>>(w1, w1pack, 128, 128, 1.0f);
    pack_w<<<dim3(64), 256, 0, stream>>>(w2, w2pack, 1024, 128, K2L);
    cde_main<<<dim3(NBLK), 1024, 0, stream>>>(ts, coeffs, x0, lin1_w, lin1_b,
        b0, b1, b2, l2w, l2b,
        (const short8*)w0pack, (const short8*)w1pack, (const short8*)w2pack,
        (float*)d_out);
}

// Round 8
// 390.080 us; speedup vs baseline: 1.0235x; 1.0235x over previous
//
#include <hip/hip_runtime.h>

// ---------------- constants ----------------
#define BTOT   4096
#define DATA   16
#define HID    64
#define VFW    128
#define LAB    10
#define TPTS   201
#define NSEG   200
#define NSTEPS 100
#define MT     16            // batch rows per block
#define NBLK   (BTOT / MT)   // 256
#define YS     68            // padded fp32 stride for y32 (logits staging only)

typedef __attribute__((ext_vector_type(8))) short short8;   // 8 bf16
typedef __attribute__((ext_vector_type(4))) float f32x4;
typedef __attribute__((ext_vector_type(2))) unsigned uint2v;

#define LOG2E  1.4426950408889634f
#define K2L    (2.0f * LOG2E)

__device__ __forceinline__ short f2bf(float f) {
    unsigned u = __builtin_bit_cast(unsigned, f);
    u = (u + 0x7FFFu + ((u >> 16) & 1u)) >> 16;   // RNE
    return (short)u;
}

// pack two f32 -> two bf16 (RNE) in one VALU op
__device__ __forceinline__ unsigned cvt_pk_bf16(float lo, float hi) {
    unsigned r;
    asm("v_cvt_pk_bf16_f32 %0, %1, %2" : "=v"(r) : "v"(lo), "v"(hi));
    return r;
}

__device__ __forceinline__ float exp2_raw(float x) {
#if __has_builtin(__builtin_amdgcn_exp2f)
    return __builtin_amdgcn_exp2f(x);
#else
    return exp2f(x);
#endif
}

// ---------------- weight fragment packing ----------------
// slot index = (nt*KS + ks)*64 + lane ; each slot = 8 bf16 (16B)
// holding scale*W[16*nt + (lane&15)][32*ks + 8*(lane>>4) + j], j=0..7
// Serves as A-fragment (row=lane&15) and B-fragment (col=lane&15).
__global__ void pack_w(const float* __restrict__ W, short* __restrict__ outp,
                       int N, int K, float scale) {
    int tid = blockIdx.x * blockDim.x + threadIdx.x;
    int KS = K >> 5;
    int total = (N >> 4) * KS * 64;
    if (tid >= total) return;
    int ln = tid & 63;
    int fs = tid >> 6;
    int ks = fs % KS;
    int nt = fs / KS;
    int n  = nt * 16 + (ln & 15);
    int k0 = ks * 32 + (ln >> 4) * 8;
    const float* src = W + n * K + k0;
    short8 v;
#pragma unroll
    for (int j = 0; j < 8; ++j) v[j] = f2bf(scale * src[j]);
    *(((short8*)outp) + tid) = v;
}

// ---------------- persistent CDE kernel ----------------
__global__ __launch_bounds__(1024, 4) void cde_main(
    const float* __restrict__ ts_g,  const float* __restrict__ coeffs,
    const float* __restrict__ x0,    const float* __restrict__ lin1_w,
    const float* __restrict__ lin1_b,
    const float* __restrict__ b0g,   const float* __restrict__ b1g,
    const float* __restrict__ b2g,   const float* __restrict__ l2w,
    const float* __restrict__ l2b,
    const short8* __restrict__ w0p,  const short8* __restrict__ w1p,
    const short8* __restrict__ w2p,  float* __restrict__ out)
{
    __shared__ float ts_sh[TPTS];
    __shared__ float ttab[NSTEPS + 1];
    __shared__ float cdtab[(NSTEPS + 1) * DATA];
    __shared__ float cdqtab[(NSTEPS + 1) * 4];       // per-quad sums of cd
    __shared__ float y32[MT * YS];                   // logits staging only
    __shared__ __align__(16) short ybf[MT * 72];     // 16x64 bf16, stride 72
    __shared__ __align__(16) short h1bf[MT * 136];   // 16x128 bf16, stride 136
    __shared__ __align__(16) short h2bf[MT * 136];
    __shared__ float b2s[HID * DATA];                // 2*log2e*b2 (MFMA C-init)
    __shared__ __align__(16) short w0f[1024 * 8];    // w0 frags (16KB)
    __shared__ __align__(16) short w1f[2048 * 8];    // w1 frags (32KB)
    __shared__ __align__(16) short w2f3[4096 * 8];   // w2 tile i=3 frags (64KB)
    __shared__ float lgts[MT * 12];

    const int tid  = threadIdx.x;
    const int lane = tid & 63;
    const int wave = tid >> 6;       // 0..15
    const int lm   = lane & 15;
    const int lg   = lane >> 4;      // 0..3
    const int row0 = blockIdx.x * MT;

    // ---- phase 0: ts ----
    for (int i = tid; i < TPTS; i += 1024) ts_sh[i] = ts_g[i];
    __syncthreads();

    const float dtv = (ts_sh[TPTS - 1] - ts_sh[0]) / 100.0f;
    const float half_dt = 0.5f * dtv;

    // ---- phase 1: ttab (exact serial t chain) + misc init ----
    if (tid == 0) {
        float tv = ts_sh[0];
        ttab[0] = tv;
        for (int s = 0; s < NSTEPS; ++s) { tv = tv + dtv; ttab[s + 1] = tv; }
    }
    for (int i = tid; i < HID * DATA; i += 1024) b2s[i] = K2L * b2g[i];
    for (int i = tid; i < 1024; i += 1024) ((short8*)w0f)[i] = w0p[i];
    for (int i = tid; i < 2048; i += 1024) ((short8*)w1f)[i] = w1p[i];

    // ---- per-lane y-state: lane (lm,lg) of wave owns y[m=lm][col=wave*4+lg] ----
    const int ycol = wave * 4 + lg;
    float yreg;
    {
        float s = lin1_b[ycol];
        const float* xr = x0 + (row0 + lm) * DATA;
        const float* wr = lin1_w + ycol * DATA;
#pragma unroll
        for (int k = 0; k < DATA; ++k) s += xr[k] * wr[k];
        yreg = s;
        ybf[lm * 72 + ycol] = f2bf(s);
    }
    __syncthreads();

    // ---- phase 2: cd table (exact reference formula, hoisted) ----
    for (int idx = tid; idx < (NSTEPS + 1) * DATA; idx += 1024) {
        float tv = ttab[idx >> 4];
        int d = idx & 15;
        int g  = (int)(tv * 200.0f);
        int i0 = g - 2; i0 = i0 < 0 ? 0 : (i0 > 196 ? 196 : i0);
        float v0 = ts_sh[i0 + 1], v1 = ts_sh[i0 + 2], v2 = ts_sh[i0 + 3], v3 = ts_sh[i0 + 4];
        int aidx = i0 + (v0 < tv) + (v1 < tv) + (v2 < tv) + (v3 < tv);
        aidx = aidx > (NSEG - 1) ? (NSEG - 1) : aidx;
        float dtl = tv - ts_sh[aidx];
        const f32x4 cc = *(const f32x4*)(coeffs + (aidx * DATA + d) * 4);
        cdtab[idx] = cc[0] + dtl * (cc[1] + dtl * (cc[2] + dtl * cc[3]));
    }
    __syncthreads();
    for (int idx = tid; idx < (NSTEPS + 1) * 4; idx += 1024) {
        const f32x4 c = *(const f32x4*)&cdtab[idx * 4];
        cdqtab[idx] = (c[0] + c[1]) + (c[2] + c[3]);
    }

    // ---- w2 tiles 0-2 -> registers (48 AGPR); tile 3 -> LDS (64KB) ----
    short8 w2r[3][4];
#pragma unroll
    for (int i = 0; i < 3; ++i)
#pragma unroll
        for (int ks = 0; ks < 4; ++ks)
            w2r[i][ks] = w2p[((wave * 4 + i) * 4 + ks) * 64 + lane];
#pragma unroll
    for (int ks = 0; ks < 4; ++ks)
        ((short8*)w2f3)[(wave * 4 + ks) * 64 + lane] =
            w2p[((wave * 4 + 3) * 4 + ks) * 64 + lane];
    // bias as per-lane f32x4 (C-init for swapped G1/G2: rows n = base + 4lg + r)
    const f32x4 bias4 = (wave < 8)
        ? *(const f32x4*)&b0g[wave * 16 + 4 * lg]
        : *(const f32x4*)&b1g[(wave - 8) * 16 + 4 * lg];
    __syncthreads();

    // one G3 tile: acc = b2-init + w2 x h2^T ; returns contraction partial
    auto g3tile = [&](short8 wa0, short8 wa1, short8 wa2, short8 wa3,
                      const short8 (&hb)[4], int nb, const f32x4& cdr) -> float {
        f32x4 acc = *(const f32x4*)&b2s[nb];          // scaled bias as C-init
        acc = __builtin_amdgcn_mfma_f32_16x16x32_bf16(wa0, hb[0], acc, 0, 0, 0);
        acc = __builtin_amdgcn_mfma_f32_16x16x32_bf16(wa1, hb[1], acc, 0, 0, 0);
        acc = __builtin_amdgcn_mfma_f32_16x16x32_bf16(wa2, hb[2], acc, 0, 0, 0);
        acc = __builtin_amdgcn_mfma_f32_16x16x32_bf16(wa3, hb[3], acc, 0, 0, 0);
        float csum = 0.f;
#pragma unroll
        for (int r = 0; r < 4; ++r) {
            // tanh(x) = 1 - 2/(e^{2x}+1);  e^{2x} = 2^acc (w2/b2 pre-scaled)
            float e  = exp2_raw(acc[r]);
            float rc = __builtin_amdgcn_rcpf(e + 1.0f);
            csum = __builtin_fmaf(cdr[r], rc, csum);
        }
        return csum;
    };

    // evalVF: K = k[m=lm][h=wave*4+lg] (lane-local result)
    auto evalVF = [&](int tidx) -> float {
        // ---- GEMM1 swapped (waves 0-7): D[n][m] = w0(16x64-tile) x y^T ----
        if (wave < 8) {
            short8 yb0 = *(const short8*)&ybf[lm * 72 + 0  + lg * 8];
            short8 yb1 = *(const short8*)&ybf[lm * 72 + 32 + lg * 8];
            short8 ws0 = ((const short8*)w0f)[(wave * 2 + 0) * 64 + lane];
            short8 ws1 = ((const short8*)w0f)[(wave * 2 + 1) * 64 + lane];
            f32x4 acc1 = bias4;
            acc1 = __builtin_amdgcn_mfma_f32_16x16x32_bf16(ws0, yb0, acc1, 0, 0, 0);
            acc1 = __builtin_amdgcn_mfma_f32_16x16x32_bf16(ws1, yb1, acc1, 0, 0, 0);
            // rows n = wave*16 + 4lg + r contiguous -> one b64 store
            unsigned lo = cvt_pk_bf16(fmaxf(acc1[0], 0.f), fmaxf(acc1[1], 0.f));
            unsigned hi = cvt_pk_bf16(fmaxf(acc1[2], 0.f), fmaxf(acc1[3], 0.f));
            uint2v st; st[0] = lo; st[1] = hi;
            *(uint2v*)&h1bf[lm * 136 + wave * 16 + 4 * lg] = st;
        }
        __syncthreads();
        // all waves: control-deriv fragment + quad-sum (broadcast reads)
        const f32x4 cdr = *(const f32x4*)&cdtab[tidx * DATA + 4 * lg];
        const float sumcd = cdqtab[tidx * 4 + lg];
        // ---- GEMM2 swapped (waves 8-15): D[n][m] = w1(16x128-tile) x h1^T ----
        if (wave >= 8) {
            const int nt = wave - 8;
            f32x4 a = bias4;
            f32x4 b = {0.f, 0.f, 0.f, 0.f};
#pragma unroll
            for (int ks = 0; ks < 2; ++ks) {
                short8 h0 = *(const short8*)&h1bf[lm * 136 + (2 * ks) * 32 + lg * 8];
                short8 h1 = *(const short8*)&h1bf[lm * 136 + (2 * ks + 1) * 32 + lg * 8];
                short8 ws0 = ((const short8*)w1f)[(nt * 4 + 2 * ks) * 64 + lane];
                short8 ws1 = ((const short8*)w1f)[(nt * 4 + 2 * ks + 1) * 64 + lane];
                a = __builtin_amdgcn_mfma_f32_16x16x32_bf16(ws0, h0, a, 0, 0, 0);
                b = __builtin_amdgcn_mfma_f32_16x16x32_bf16(ws1, h1, b, 0, 0, 0);
            }
            f32x4 acc2 = a + b;
            unsigned lo = cvt_pk_bf16(fmaxf(acc2[0], 0.f), fmaxf(acc2[1], 0.f));
            unsigned hi = cvt_pk_bf16(fmaxf(acc2[2], 0.f), fmaxf(acc2[3], 0.f));
            uint2v st; st[0] = lo; st[1] = hi;
            *(uint2v*)&h2bf[lm * 136 + nt * 16 + 4 * lg] = st;
        }
        __syncthreads();
        // ---- GEMM3 (all 16 waves, 4 n-tiles: 3 AGPR + 1 LDS) + tanh/contract ----
        short8 hb[4];
#pragma unroll
        for (int ks = 0; ks < 4; ++ks)
            hb[ks] = *(const short8*)&h2bf[lm * 136 + ks * 32 + lg * 8];
        short8 w2l0 = ((const short8*)w2f3)[(wave * 4 + 0) * 64 + lane];
        short8 w2l1 = ((const short8*)w2f3)[(wave * 4 + 1) * 64 + lane];
        short8 w2l2 = ((const short8*)w2f3)[(wave * 4 + 2) * 64 + lane];
        short8 w2l3 = ((const short8*)w2f3)[(wave * 4 + 3) * 64 + lane];
        const int nb0 = (wave * 4) * 16 + 4 * lg;     // n = h*16 + d, d = 4lg+r
        float c0 = g3tile(w2r[0][0], w2r[0][1], w2r[0][2], w2r[0][3], hb, nb0,      cdr);
        float c1 = g3tile(w2r[1][0], w2r[1][1], w2r[1][2], w2r[1][3], hb, nb0 + 16, cdr);
        float c2 = g3tile(w2r[2][0], w2r[2][1], w2r[2][2], w2r[2][3], hb, nb0 + 32, cdr);
        float c3 = g3tile(w2l0, w2l1, w2l2, w2l3,                     hb, nb0 + 48, cdr);
        float p0 = __builtin_fmaf(c0, -2.0f, sumcd);
        float p1 = __builtin_fmaf(c1, -2.0f, sumcd);
        float p2 = __builtin_fmaf(c2, -2.0f, sumcd);
        float p3 = __builtin_fmaf(c3, -2.0f, sumcd);
        // ---- transpose-reduce over lg: K = sum_lg' p_{lg}(lg') lands at lane lg ----
        bool g1 = (lg & 1) != 0;
        float a4 = (lg & 2) ? p2 : p0;
        float b4 = (lg & 2) ? p3 : p1;
        float c4 = (lg & 2) ? p0 : p2;
        float d4 = (lg & 2) ? p1 : p3;
        float pg  = g1 ? b4 : a4;      // p[g]
        float pg1 = g1 ? a4 : b4;      // p[g^1]
        float pg2 = g1 ? d4 : c4;      // p[g^2]
        float pg3 = g1 ? c4 : d4;      // p[g^3]
        float s1  = pg  + __shfl_xor(pg1, 16);
        float s1b = pg2 + __shfl_xor(pg3, 16);
        return s1 + __shfl_xor(s1b, 32);
    };

    // ---- Heun time loop (y fully register-resident, lane-local) ----
    const int yboff = lm * 72 + ycol;
    for (int s = 0; s < NSTEPS; ++s) {
        float K1 = evalVF(s);
        ybf[yboff] = (short)cvt_pk_bf16(__builtin_fmaf(dtv, K1, yreg), 0.f);
        yreg = __builtin_fmaf(half_dt, K1, yreg);             // y + dt/2*k1
        __syncthreads();
        float K2 = evalVF(s + 1);
        yreg = __builtin_fmaf(half_dt, K2, yreg);             // full Heun update
        ybf[yboff] = (short)cvt_pk_bf16(yreg, 0.f);
        __syncthreads();
    }

    // ---- logits + softmax (fp32 scalar) ----
    y32[lm * YS + ycol] = yreg;
    __syncthreads();
    if (tid < MT * LAB) {
        int m = tid / LAB, j = tid % LAB;
        float s = l2b[j];
        const float* wr = l2w + j * HID;
#pragma unroll
        for (int h = 0; h < HID; ++h) s += y32[m * YS + h] * wr[h];
        lgts[m * 12 + j] = s;
    }
    __syncthreads();
    if (tid < MT) {
        int m = tid;
        float mx = lgts[m * 12];
#pragma unroll
        for (int j = 1; j < LAB; ++j) mx = fmaxf(mx, lgts[m * 12 + j]);
        float e[LAB]; float sum = 0.f;
#pragma unroll
        for (int j = 0; j < LAB; ++j) { e[j] = __expf(lgts[m * 12 + j] - mx); sum += e[j]; }
#pragma unroll
        for (int j = 0; j < LAB; ++j) out[(row0 + m) * LAB + j] = e[j] / sum;
    }
}

extern "C" void kernel_launch(void* const* d_in, const int* in_sizes, int n_in,
                              void* d_out, int out_size, void* d_ws, size_t ws_size,
                              hipStream_t stream) {
    (void)in_sizes; (void)n_in; (void)out_size; (void)ws_size;
    const float* ts     = (const float*)d_in[0];
    const float* coeffs = (const float*)d_in[1];
    const float* x0     = (const float*)d_in[2];
    const float* lin1_w = (const float*)d_in[3];
    const float* lin1_b = (const float*)d_in[4];
    const float* w0     = (const float*)d_in[5];
    const float* b0     = (const float*)d_in[6];
    const float* w1     = (const float*)d_in[7];
    const float* b1     = (const float*)d_in[8];
    const float* w2     = (const float*)d_in[9];
    const float* b2     = (const float*)d_in[10];
    const float* l2w    = (const float*)d_in[11];
    const float* l2b    = (const float*)d_in[12];

    short* w0pack = (short*)d_ws;                           // 16 KB
    short* w1pack = (short*)((char*)d_ws + 16384);          // 32 KB
    short* w2pack = (short*)((char*)d_ws + 49152);          // 256 KB

    pack_w<<<dim3(4),  256, 0, stream>>>(w0, w0pack, 128, 64,  1.0f);
    pack_w<<<dim3(8),  256, 0, stream>>>(w1, w1pack, 128, 128, 1.0f);
    pack_w<<<dim3(64), 256, 0, stream>>>(w2, w2pack, 1024, 128, K2L);
    cde_main<<<dim3(NBLK), 1024, 0, stream>>>(ts, coeffs, x0, lin1_w, lin1_b,
        b0, b1, b2, l2w, l2b,
        (const short8*)w0pack, (const short8*)w1pack, (const short8*)w2pack,
        (float*)d_out);
}

// Round 10
// 382.578 us; speedup vs baseline: 1.0436x; 1.0196x over previous
//
#include <hip/hip_runtime.h>

// ---------------- constants ----------------
#define BTOT   4096
#define DATA   16
#define HID    64
#define VFW    128
#define LAB    10
#define TPTS   201
#define NSEG   200
#define NSTEPS 100
#define MT     16            // batch rows per block
#define NBLK   (BTOT / MT)   // 256
#define YS     68            // padded fp32 stride for y32 (logits staging only)

typedef __attribute__((ext_vector_type(8))) short short8;   // 8 bf16
typedef __attribute__((ext_vector_type(4))) float f32x4;
typedef __attribute__((ext_vector_type(2))) unsigned uint2v;

#define LOG2E  1.4426950408889634f
#define K2L    (2.0f * LOG2E)

__device__ __forceinline__ short f2bf(float f) {
    unsigned u = __builtin_bit_cast(unsigned, f);
    u = (u + 0x7FFFu + ((u >> 16) & 1u)) >> 16;   // RNE
    return (short)u;
}

// pack two f32 -> two bf16 (RNE) in one VALU op
__device__ __forceinline__ unsigned cvt_pk_bf16(float lo, float hi) {
    unsigned r;
    asm("v_cvt_pk_bf16_f32 %0, %1, %2" : "=v"(r) : "v"(lo), "v"(hi));
    return r;
}

__device__ __forceinline__ float exp2_raw(float x) {
#if __has_builtin(__builtin_amdgcn_exp2f)
    return __builtin_amdgcn_exp2f(x);
#else
    return exp2f(x);
#endif
}

// ---------------- weight fragment packing ----------------
// slot index = (nt*KS + ks)*64 + lane ; each slot = 8 bf16 (16B)
// holding scale*W[16*nt + (lane&15)][32*ks + 8*(lane>>4) + j], j=0..7
// Serves as A-fragment (row=lane&15) and B-fragment (col=lane&15).
__global__ void pack_w(const float* __restrict__ W, short* __restrict__ outp,
                       int N, int K, float scale) {
    int tid = blockIdx.x * blockDim.x + threadIdx.x;
    int KS = K >> 5;
    int total = (N >> 4) * KS * 64;
    if (tid >= total) return;
    int ln = tid & 63;
    int fs = tid >> 6;
    int ks = fs % KS;
    int nt = fs / KS;
    int n  = nt * 16 + (ln & 15);
    int k0 = ks * 32 + (ln >> 4) * 8;
    const float* src = W + n * K + k0;
    short8 v;
#pragma unroll
    for (int j = 0; j < 8; ++j) v[j] = f2bf(scale * src[j]);
    *(((short8*)outp) + tid) = v;
}

// ---------------- persistent CDE kernel ----------------
__global__ __launch_bounds__(1024, 4) void cde_main(
    const float* __restrict__ ts_g,  const float* __restrict__ coeffs,
    const float* __restrict__ x0,    const float* __restrict__ lin1_w,
    const float* __restrict__ lin1_b,
    const float* __restrict__ b0g,   const float* __restrict__ b1g,
    const float* __restrict__ b2g,   const float* __restrict__ l2w,
    const float* __restrict__ l2b,
    const short8* __restrict__ w0p,  const short8* __restrict__ w1p,
    const short8* __restrict__ w2p,  float* __restrict__ out)
{
    __shared__ float ts_sh[TPTS];
    __shared__ float ttab[NSTEPS + 1];
    __shared__ float cdtab[(NSTEPS + 1) * DATA];
    __shared__ float cdqtab[(NSTEPS + 1) * 4];       // per-quad sums of cd
    __shared__ float y32[MT * YS];                   // logits staging only
    __shared__ __align__(16) short ybf[MT * 72];     // 16x64 bf16, stride 72
    __shared__ __align__(16) short h1bf[MT * 136];   // 16x128 bf16, stride 136
    __shared__ __align__(16) short h2bf[MT * 136];
    __shared__ float b2s[HID * DATA];                // 2*log2e*b2 (MFMA C-init)
    __shared__ __align__(16) short w0f[1024 * 8];    // w0 frags (16KB)
    __shared__ __align__(16) short w1f[2048 * 8];    // w1 frags (32KB)
    __shared__ __align__(16) short w2f3[4096 * 8];   // w2 tile i=3 frags (64KB)
    __shared__ float lgts[MT * 12];

    const int tid  = threadIdx.x;
    const int lane = tid & 63;
    const int wave = tid >> 6;       // 0..15
    const int lm   = lane & 15;
    const int lg   = lane >> 4;      // 0..3
    const int row0 = blockIdx.x * MT;

    // ---- phase 0: ts ----
    for (int i = tid; i < TPTS; i += 1024) ts_sh[i] = ts_g[i];
    __syncthreads();

    const float dtv = (ts_sh[TPTS - 1] - ts_sh[0]) / 100.0f;
    const float half_dt = 0.5f * dtv;

    // ---- phase 1: ttab (exact serial t chain) + misc init ----
    if (tid == 0) {
        float tv = ts_sh[0];
        ttab[0] = tv;
        for (int s = 0; s < NSTEPS; ++s) { tv = tv + dtv; ttab[s + 1] = tv; }
    }
    for (int i = tid; i < HID * DATA; i += 1024) b2s[i] = K2L * b2g[i];
    for (int i = tid; i < 1024; i += 1024) ((short8*)w0f)[i] = w0p[i];
    for (int i = tid; i < 2048; i += 1024) ((short8*)w1f)[i] = w1p[i];

    // ---- per-lane y-state: lane (lm,lg) of wave owns y[m=lm][col=wave*4+lg] ----
    const int ycol = wave * 4 + lg;
    float yreg;
    {
        float s = lin1_b[ycol];
        const float* xr = x0 + (row0 + lm) * DATA;
        const float* wr = lin1_w + ycol * DATA;
#pragma unroll
        for (int k = 0; k < DATA; ++k) s += xr[k] * wr[k];
        yreg = s;
        ybf[lm * 72 + ycol] = f2bf(s);
    }
    __syncthreads();

    // ---- phase 2: cd table (exact reference formula, hoisted) ----
    for (int idx = tid; idx < (NSTEPS + 1) * DATA; idx += 1024) {
        float tv = ttab[idx >> 4];
        int d = idx & 15;
        int g  = (int)(tv * 200.0f);
        int i0 = g - 2; i0 = i0 < 0 ? 0 : (i0 > 196 ? 196 : i0);
        float v0 = ts_sh[i0 + 1], v1 = ts_sh[i0 + 2], v2 = ts_sh[i0 + 3], v3 = ts_sh[i0 + 4];
        int aidx = i0 + (v0 < tv) + (v1 < tv) + (v2 < tv) + (v3 < tv);
        aidx = aidx > (NSEG - 1) ? (NSEG - 1) : aidx;
        float dtl = tv - ts_sh[aidx];
        const f32x4 cc = *(const f32x4*)(coeffs + (aidx * DATA + d) * 4);
        cdtab[idx] = cc[0] + dtl * (cc[1] + dtl * (cc[2] + dtl * cc[3]));
    }
    __syncthreads();
    for (int idx = tid; idx < (NSTEPS + 1) * 4; idx += 1024) {
        const f32x4 c = *(const f32x4*)&cdtab[idx * 4];
        cdqtab[idx] = (c[0] + c[1]) + (c[2] + c[3]);
    }

    // ---- w2 tiles 0-2 -> registers (48 AGPR); tile 3 -> LDS (64KB) ----
    short8 w2r[3][4];
#pragma unroll
    for (int i = 0; i < 3; ++i)
#pragma unroll
        for (int ks = 0; ks < 4; ++ks)
            w2r[i][ks] = w2p[((wave * 4 + i) * 4 + ks) * 64 + lane];
#pragma unroll
    for (int ks = 0; ks < 4; ++ks)
        ((short8*)w2f3)[(wave * 4 + ks) * 64 + lane] =
            w2p[((wave * 4 + 3) * 4 + ks) * 64 + lane];
    // bias as per-lane f32x4 (C-init for swapped G1/G2: rows n = base + 4lg + r)
    const f32x4 bias4 = (wave < 8)
        ? *(const f32x4*)&b0g[wave * 16 + 4 * lg]
        : *(const f32x4*)&b1g[(wave - 8) * 16 + 4 * lg];
    __syncthreads();

    // one G3 tile: acc = b2-init + w2 x h2^T ; returns contraction partial.
    // setprio(1) around the MFMA quad (T5): anti-aligns waves so one wave's
    // MFMA burst overlaps another's tanh/trans block.
    auto g3tile = [&](short8 wa0, short8 wa1, short8 wa2, short8 wa3,
                      const short8 (&hb)[4], int nb, const f32x4& cdr) -> float {
        f32x4 acc = *(const f32x4*)&b2s[nb];          // scaled bias as C-init
        __builtin_amdgcn_s_setprio(1);
        acc = __builtin_amdgcn_mfma_f32_16x16x32_bf16(wa0, hb[0], acc, 0, 0, 0);
        acc = __builtin_amdgcn_mfma_f32_16x16x32_bf16(wa1, hb[1], acc, 0, 0, 0);
        acc = __builtin_amdgcn_mfma_f32_16x16x32_bf16(wa2, hb[2], acc, 0, 0, 0);
        acc = __builtin_amdgcn_mfma_f32_16x16x32_bf16(wa3, hb[3], acc, 0, 0, 0);
        __builtin_amdgcn_s_setprio(0);
        float csum = 0.f;
#pragma unroll
        for (int r = 0; r < 4; ++r) {
            // tanh(x) = 1 - 2/(e^{2x}+1);  e^{2x} = 2^acc (w2/b2 pre-scaled)
            float e  = exp2_raw(acc[r]);
            float rc = __builtin_amdgcn_rcpf(e + 1.0f);
            csum = __builtin_fmaf(cdr[r], rc, csum);
        }
        return csum;
    };

    // evalVF: K = k[m=lm][h=wave*4+lg] (lane-local result)
    auto evalVF = [&](int tidx) -> float {
        // ---- GEMM1 swapped (waves 0-7): D[n][m] = w0(16x64-tile) x y^T ----
        if (wave < 8) {
            short8 yb0 = *(const short8*)&ybf[lm * 72 + 0  + lg * 8];
            short8 yb1 = *(const short8*)&ybf[lm * 72 + 32 + lg * 8];
            short8 ws0 = ((const short8*)w0f)[(wave * 2 + 0) * 64 + lane];
            short8 ws1 = ((const short8*)w0f)[(wave * 2 + 1) * 64 + lane];
            f32x4 acc1 = bias4;
            acc1 = __builtin_amdgcn_mfma_f32_16x16x32_bf16(ws0, yb0, acc1, 0, 0, 0);
            acc1 = __builtin_amdgcn_mfma_f32_16x16x32_bf16(ws1, yb1, acc1, 0, 0, 0);
            // rows n = wave*16 + 4lg + r contiguous -> one b64 store
            unsigned lo = cvt_pk_bf16(fmaxf(acc1[0], 0.f), fmaxf(acc1[1], 0.f));
            unsigned hi = cvt_pk_bf16(fmaxf(acc1[2], 0.f), fmaxf(acc1[3], 0.f));
            uint2v st; st[0] = lo; st[1] = hi;
            *(uint2v*)&h1bf[lm * 136 + wave * 16 + 4 * lg] = st;
        }
        __syncthreads();
        // all waves: control-deriv fragment + quad-sum (broadcast reads)
        const f32x4 cdr = *(const f32x4*)&cdtab[tidx * DATA + 4 * lg];
        const float sumcd = cdqtab[tidx * 4 + lg];
        // ---- GEMM2 swapped (waves 8-15): D[n][m] = w1(16x128-tile) x h1^T ----
        if (wave >= 8) {
            const int nt = wave - 8;
            f32x4 a = bias4;
            f32x4 b = {0.f, 0.f, 0.f, 0.f};
#pragma unroll
            for (int ks = 0; ks < 2; ++ks) {
                short8 h0 = *(const short8*)&h1bf[lm * 136 + (2 * ks) * 32 + lg * 8];
                short8 h1 = *(const short8*)&h1bf[lm * 136 + (2 * ks + 1) * 32 + lg * 8];
                short8 ws0 = ((const short8*)w1f)[(nt * 4 + 2 * ks) * 64 + lane];
                short8 ws1 = ((const short8*)w1f)[(nt * 4 + 2 * ks + 1) * 64 + lane];
                a = __builtin_amdgcn_mfma_f32_16x16x32_bf16(ws0, h0, a, 0, 0, 0);
                b = __builtin_amdgcn_mfma_f32_16x16x32_bf16(ws1, h1, b, 0, 0, 0);
            }
            f32x4 acc2 = a + b;
            unsigned lo = cvt_pk_bf16(fmaxf(acc2[0], 0.f), fmaxf(acc2[1], 0.f));
            unsigned hi = cvt_pk_bf16(fmaxf(acc2[2], 0.f), fmaxf(acc2[3], 0.f));
            uint2v st; st[0] = lo; st[1] = hi;
            *(uint2v*)&h2bf[lm * 136 + nt * 16 + 4 * lg] = st;
        }
        __syncthreads();
        // ---- GEMM3 (all 16 waves, 4 n-tiles: 3 AGPR + 1 LDS) + tanh/contract ----
        short8 hb[4];
#pragma unroll
        for (int ks = 0; ks < 4; ++ks)
            hb[ks] = *(const short8*)&h2bf[lm * 136 + ks * 32 + lg * 8];
        short8 w2l0 = ((const short8*)w2f3)[(wave * 4 + 0) * 64 + lane];
        short8 w2l1 = ((const short8*)w2f3)[(wave * 4 + 1) * 64 + lane];
        short8 w2l2 = ((const short8*)w2f3)[(wave * 4 + 2) * 64 + lane];
        short8 w2l3 = ((const short8*)w2f3)[(wave * 4 + 3) * 64 + lane];
        const int nb0 = (wave * 4) * 16 + 4 * lg;     // n = h*16 + d, d = 4lg+r
        float c0 = g3tile(w2r[0][0], w2r[0][1], w2r[0][2], w2r[0][3], hb, nb0,      cdr);
        float c1 = g3tile(w2r[1][0], w2r[1][1], w2r[1][2], w2r[1][3], hb, nb0 + 16, cdr);
        float c2 = g3tile(w2r[2][0], w2r[2][1], w2r[2][2], w2r[2][3], hb, nb0 + 32, cdr);
        float c3 = g3tile(w2l0, w2l1, w2l2, w2l3,                     hb, nb0 + 48, cdr);
        float p0 = __builtin_fmaf(c0, -2.0f, sumcd);
        float p1 = __builtin_fmaf(c1, -2.0f, sumcd);
        float p2 = __builtin_fmaf(c2, -2.0f, sumcd);
        float p3 = __builtin_fmaf(c3, -2.0f, sumcd);
        // ---- transpose-reduce over lg: K = sum_lg' p_{lg}(lg') lands at lane lg ----
        bool g1 = (lg & 1) != 0;
        float a4 = (lg & 2) ? p2 : p0;
        float b4 = (lg & 2) ? p3 : p1;
        float c4 = (lg & 2) ? p0 : p2;
        float d4 = (lg & 2) ? p1 : p3;
        float pg  = g1 ? b4 : a4;      // p[g]
        float pg1 = g1 ? a4 : b4;      // p[g^1]
        float pg2 = g1 ? d4 : c4;      // p[g^2]
        float pg3 = g1 ? c4 : d4;      // p[g^3]
        float s1  = pg  + __shfl_xor(pg1, 16);
        float s1b = pg2 + __shfl_xor(pg3, 16);
        return s1 + __shfl_xor(s1b, 32);
    };

    // ---- Heun time loop (y fully register-resident, lane-local) ----
    const int yboff = lm * 72 + ycol;
    for (int s = 0; s < NSTEPS; ++s) {
        float K1 = evalVF(s);
        ybf[yboff] = (short)cvt_pk_bf16(__builtin_fmaf(dtv, K1, yreg), 0.f);
        yreg = __builtin_fmaf(half_dt, K1, yreg);             // y + dt/2*k1
        __syncthreads();
        float K2 = evalVF(s + 1);
        yreg = __builtin_fmaf(half_dt, K2, yreg);             // full Heun update
        ybf[yboff] = (short)cvt_pk_bf16(yreg, 0.f);
        __syncthreads();
    }

    // ---- logits + softmax (fp32 scalar) ----
    y32[lm * YS + ycol] = yreg;
    __syncthreads();
    if (tid < MT * LAB) {
        int m = tid / LAB, j = tid % LAB;
        float s = l2b[j];
        const float* wr = l2w + j * HID;
#pragma unroll
        for (int h = 0; h < HID; ++h) s += y32[m * YS + h] * wr[h];
        lgts[m * 12 + j] = s;
    }
    __syncthreads();
    if (tid < MT) {
        int m = tid;
        float mx = lgts[m * 12];
#pragma unroll
        for (int j = 1; j < LAB; ++j) mx = fmaxf(mx, lgts[m * 12 + j]);
        float e[LAB]; float sum = 0.f;
#pragma unroll
        for (int j = 0; j < LAB; ++j) { e[j] = __expf(lgts[m * 12 + j] - mx); sum += e[j]; }
#pragma unroll
        for (int j = 0; j < LAB; ++j) out[(row0 + m) * LAB + j] = e[j] / sum;
    }
}

extern "C" void kernel_launch(void* const* d_in, const int* in_sizes, int n_in,
                              void* d_out, int out_size, void* d_ws, size_t ws_size,
                              hipStream_t stream) {
    (void)in_sizes; (void)n_in; (void)out_size; (void)ws_size;
    const float* ts     = (const float*)d_in[0];
    const float* coeffs = (const float*)d_in[1];
    const float* x0     = (const float*)d_in[2];
    const float* lin1_w = (const float*)d_in[3];
    const float* lin1_b = (const float*)d_in[4];
    const float* w0     = (const float*)d_in[5];
    const float* b0     = (const float*)d_in[6];
    const float* w1     = (const float*)d_in[7];
    const float* b1     = (const float*)d_in[8];
    const float* w2     = (const float*)d_in[9];
    const float* b2     = (const float*)d_in[10];
    const float* l2w    = (const float*)d_in[11];
    const float* l2b    = (const float*)d_in[12];

    short* w0pack = (short*)d_ws;                           // 16 KB
    short* w1pack = (short*)((char*)d_ws + 16384);          // 32 KB
    short* w2pack = (short*)((char*)d_ws + 49152);          // 256 KB

    pack_w<<<dim3(4),  256, 0, stream>>>(w0, w0pack, 128, 64,  1.0f);
    pack_w<<<dim3(8),  256, 0, stream>>>(w1, w1pack, 128, 128, 1.0f);
    pack_w<<<dim3(64), 256, 0, stream>>>(w2, w2pack, 1024, 128, K2L);
    cde_main<<<dim3(NBLK), 1024, 0, stream>>>(ts, coeffs, x0, lin1_w, lin1_b,
        b0, b1, b2, l2w, l2b,
        (const short8*)w0pack, (const short8*)w1pack, (const short8*)w2pack,
        (float*)d_out);
}